// Round 1
// baseline (3249.024 us; speedup 1.0000x reference)
//
#include <hip/hip_runtime.h>

#define NN 50000
#define NE 800000

// ---------------- degree histogram ----------------
__global__ void count_kernel(const int* __restrict__ col, int* __restrict__ cnt, int E) {
    int e = blockIdx.x * blockDim.x + threadIdx.x;
    if (e < E) atomicAdd(&cnt[col[e]], 1);
}

// ---------------- exclusive scan (single block) + dinv ----------------
__global__ __launch_bounds__(1024) void scan_dinv_kernel(const int* __restrict__ cnt,
                                                         int* __restrict__ offs,
                                                         float* __restrict__ dinv, int N) {
    __shared__ int sums[1024];
    const int T = 1024;
    int tid = threadIdx.x;
    int chunk = (N + T - 1) / T;
    int start = tid * chunk;
    int end = start + chunk; if (end > N) end = N;
    int s = 0;
    for (int i = start; i < end; ++i) s += cnt[i];
    sums[tid] = s;
    __syncthreads();
    for (int off = 1; off < T; off <<= 1) {
        int v = (tid >= off) ? sums[tid - off] : 0;
        __syncthreads();
        sums[tid] += v;
        __syncthreads();
    }
    int run = sums[tid] - s;  // exclusive prefix
    for (int i = start; i < end; ++i) {
        offs[i] = run;
        int c = cnt[i];
        run += c;
        dinv[i] = rsqrtf((float)(c + 1));  // +1 self-loop; always > 0
    }
    if (tid == T - 1) offs[N] = sums[T - 1];
}

// ---------------- CSR fill (by target node) ----------------
__global__ void fill_kernel(const int* __restrict__ erow, const int* __restrict__ ecol,
                            const int* __restrict__ offs, int* __restrict__ cursor,
                            const float* __restrict__ dinv,
                            int* __restrict__ csr_src, float* __restrict__ csr_norm, int E) {
    int e = blockIdx.x * blockDim.x + threadIdx.x;
    if (e >= E) return;
    int r = erow[e], c = ecol[e];
    int p = atomicAdd(&cursor[c], 1);
    int idx = offs[c] + p;
    csr_src[idx] = r;
    csr_norm[idx] = dinv[r] * dinv[c];
}

// ---------------- fp32 GEMM: C[M,Nc] = A[M,256] @ B[256,Nc] ----------------
// 64x64 tile, 256 threads, 4x4 micro-tile, K-tile 16.
__global__ __launch_bounds__(256) void gemm_kernel(const float* __restrict__ A,
                                                   const float* __restrict__ B,
                                                   float* __restrict__ C, int M, int Nc) {
    __shared__ float As[16][68];  // transposed [k][m], stride 68 keeps 16B align, breaks pow2
    __shared__ float Bs[16][64];
    int tx = threadIdx.x & 15;
    int ty = threadIdx.x >> 4;
    int row0 = blockIdx.y * 64;
    int col0 = blockIdx.x * 64;

    // A tile load: thread t -> row t/4, k-quad t%4
    int la_r = threadIdx.x >> 2;
    int la_k = (threadIdx.x & 3) << 2;
    // B tile load: thread t -> k-row t/16, col-quad t%16
    int lb_k = threadIdx.x >> 4;
    int lb_c = (threadIdx.x & 15) << 2;

    float acc[4][4] = {};
    for (int k0 = 0; k0 < 256; k0 += 16) {
        float4 av = make_float4(0.f, 0.f, 0.f, 0.f);
        int ar = row0 + la_r;
        if (ar < M) av = *(const float4*)(A + (size_t)ar * 256 + k0 + la_k);
        float4 bv = *(const float4*)(B + (size_t)(k0 + lb_k) * Nc + col0 + lb_c);
        __syncthreads();
        As[la_k + 0][la_r] = av.x;
        As[la_k + 1][la_r] = av.y;
        As[la_k + 2][la_r] = av.z;
        As[la_k + 3][la_r] = av.w;
        *(float4*)&Bs[lb_k][lb_c] = bv;
        __syncthreads();
#pragma unroll
        for (int kk = 0; kk < 16; ++kk) {
            float4 a = *(const float4*)&As[kk][ty << 2];
            float4 b = *(const float4*)&Bs[kk][tx << 2];
            float aa[4] = {a.x, a.y, a.z, a.w};
            float bb[4] = {b.x, b.y, b.z, b.w};
#pragma unroll
            for (int i = 0; i < 4; ++i)
#pragma unroll
                for (int j = 0; j < 4; ++j) acc[i][j] += aa[i] * bb[j];
        }
    }
#pragma unroll
    for (int i = 0; i < 4; ++i) {
        int r = row0 + (ty << 2) + i;
        if (r < M) {
            float4 v = make_float4(acc[i][0], acc[i][1], acc[i][2], acc[i][3]);
            *(float4*)(C + (size_t)r * Nc + col0 + (tx << 2)) = v;
        }
    }
}

// ---------------- aggregation: 256 channels, one node per block ----------------
__global__ __launch_bounds__(256) void agg_kernel(const float* __restrict__ Hlin,
                                                  const float* __restrict__ dinv,
                                                  const int* __restrict__ offs,
                                                  const int* __restrict__ csr_src,
                                                  const float* __restrict__ csr_norm,
                                                  const float* __restrict__ bias,
                                                  float* __restrict__ Hout) {
    int node = blockIdx.x;
    int c = threadIdx.x;
    float di = dinv[node];
    float acc = bias[c] + di * di * Hlin[(size_t)node * 256 + c];
    int s = offs[node], e = offs[node + 1];
    for (int j = s; j < e; ++j) {
        acc += csr_norm[j] * Hlin[(size_t)csr_src[j] * 256 + c];
    }
    Hout[(size_t)node * 256 + c] = acc;
}

// ---------------- dual aggregation: mu (128) + logstd (128) ----------------
__global__ __launch_bounds__(256) void agg_dual_kernel(const float* __restrict__ MuLin,
                                                       const float* __restrict__ LsLin,
                                                       const float* __restrict__ dinv,
                                                       const int* __restrict__ offs,
                                                       const int* __restrict__ csr_src,
                                                       const float* __restrict__ csr_norm,
                                                       const float* __restrict__ bm,
                                                       const float* __restrict__ bl,
                                                       float* __restrict__ out_mu,
                                                       float* __restrict__ out_ls) {
    int node = blockIdx.x;
    int t = threadIdx.x;
    const float* Lin = (t < 128) ? MuLin : LsLin;
    const float* bias = (t < 128) ? bm : bl;
    float* out = (t < 128) ? out_mu : out_ls;
    int c = t & 127;
    float di = dinv[node];
    float acc = bias[c] + di * di * Lin[(size_t)node * 128 + c];
    int s = offs[node], e = offs[node + 1];
    for (int j = s; j < e; ++j) {
        acc += csr_norm[j] * Lin[(size_t)csr_src[j] * 128 + c];
    }
    out[(size_t)node * 128 + c] = acc;
}

extern "C" void kernel_launch(void* const* d_in, const int* in_sizes, int n_in,
                              void* d_out, int out_size, void* d_ws, size_t ws_size,
                              hipStream_t stream) {
    const int N = NN, E = NE;
    const float* Wc = (const float*)d_in[8];
    const float* bc = (const float*)d_in[9];
    const float* Wm = (const float*)d_in[10];
    const float* bm = (const float*)d_in[11];
    const float* Wl = (const float*)d_in[12];
    const float* bl = (const float*)d_in[13];
    float* out = (float*)d_out;

    // workspace layout (~110 MB)
    float* buf_lin  = (float*)d_ws;                     // N*256
    float* buf_h    = buf_lin + (size_t)N * 256;        // N*256
    float* dinv     = buf_h + (size_t)N * 256;          // N
    int*   cnt      = (int*)(dinv + N);                 // N
    int*   offs     = cnt + N;                          // N+1
    int*   cursor   = offs + N + 1;                     // N
    int*   csr_src  = cursor + N;                       // E
    float* csr_norm = (float*)(csr_src + E);            // E

    for (int g = 0; g < 4; ++g) {
        const float* x = (const float*)d_in[2 * g];
        const int* ei = (const int*)d_in[2 * g + 1];
        const int* erow = ei;       // sources
        const int* ecol = ei + E;   // targets

        hipMemsetAsync(cnt, 0, N * sizeof(int), stream);
        hipMemsetAsync(cursor, 0, N * sizeof(int), stream);
        count_kernel<<<(E + 255) / 256, 256, 0, stream>>>(ecol, cnt, E);
        scan_dinv_kernel<<<1, 1024, 0, stream>>>(cnt, offs, dinv, N);
        fill_kernel<<<(E + 255) / 256, 256, 0, stream>>>(erow, ecol, offs, cursor, dinv,
                                                         csr_src, csr_norm, E);
        // conv1: h = agg(x @ Wc) + bc
        gemm_kernel<<<dim3(256 / 64, (N + 63) / 64), 256, 0, stream>>>(
            x, Wc + (size_t)g * 256 * 256, buf_lin, N, 256);
        agg_kernel<<<N, 256, 0, stream>>>(buf_lin, dinv, offs, csr_src, csr_norm,
                                          bc + (size_t)g * 256, buf_h);
        // conv2/conv3 linears (reuse buf_lin as [mu_lin | ls_lin])
        float* mu_lin = buf_lin;
        float* ls_lin = buf_lin + (size_t)N * 128;
        gemm_kernel<<<dim3(128 / 64, (N + 63) / 64), 256, 0, stream>>>(
            buf_h, Wm + (size_t)g * 256 * 128, mu_lin, N, 128);
        gemm_kernel<<<dim3(128 / 64, (N + 63) / 64), 256, 0, stream>>>(
            buf_h, Wl + (size_t)g * 256 * 128, ls_lin, N, 128);
        agg_dual_kernel<<<N, 256, 0, stream>>>(mu_lin, ls_lin, dinv, offs, csr_src, csr_norm,
                                               bm + (size_t)g * 128, bl + (size_t)g * 128,
                                               out + (size_t)g * N * 128,
                                               out + (size_t)(4 + g) * N * 128);
    }
}

// Round 2
// 2973.588 us; speedup vs baseline: 1.0926x; 1.0926x over previous
//
#include <hip/hip_runtime.h>

#define NN 50000
#define NE 800000

typedef __attribute__((ext_vector_type(8))) short short8;
typedef __attribute__((ext_vector_type(4))) short short4v;
typedef __attribute__((ext_vector_type(4))) float floatx4;

// ---- bf16 split helpers: x ~= hi(trunc) + lo(RNE) , error ~2^-17 |x| ----
__device__ inline unsigned short bf16_hi_trunc(float x) {
    return (unsigned short)(__builtin_bit_cast(unsigned, x) >> 16);
}
__device__ inline unsigned short bf16_lo_rne(float x) {
    unsigned hu = __builtin_bit_cast(unsigned, x) & 0xFFFF0000u;
    float rest = x - __builtin_bit_cast(float, hu);
    unsigned r = __builtin_bit_cast(unsigned, rest);
    r += 0x7FFFu + ((r >> 16) & 1u);
    return (unsigned short)(r >> 16);
}
__device__ inline unsigned short bf16_rne(float x) {
    unsigned r = __builtin_bit_cast(unsigned, x);
    r += 0x7FFFu + ((r >> 16) & 1u);
    return (unsigned short)(r >> 16);
}

// ---------------- degree histogram ----------------
__global__ void count_kernel(const int* __restrict__ col, int* __restrict__ cnt, int E) {
    int e = blockIdx.x * blockDim.x + threadIdx.x;
    if (e < E) atomicAdd(&cnt[col[e]], 1);
}

// ---------------- exclusive scan (single block) + dinv ----------------
__global__ __launch_bounds__(1024) void scan_dinv_kernel(const int* __restrict__ cnt,
                                                         int* __restrict__ offs,
                                                         float* __restrict__ dinv, int N) {
    __shared__ int sums[1024];
    const int T = 1024;
    int tid = threadIdx.x;
    int chunk = (N + T - 1) / T;
    int start = tid * chunk;
    int end = start + chunk; if (end > N) end = N;
    int s = 0;
    for (int i = start; i < end; ++i) s += cnt[i];
    sums[tid] = s;
    __syncthreads();
    for (int off = 1; off < T; off <<= 1) {
        int v = (tid >= off) ? sums[tid - off] : 0;
        __syncthreads();
        sums[tid] += v;
        __syncthreads();
    }
    int run = sums[tid] - s;  // exclusive prefix
    for (int i = start; i < end; ++i) {
        offs[i] = run;
        int c = cnt[i];
        run += c;
        dinv[i] = rsqrtf((float)(c + 1));  // +1 self-loop; always > 0
    }
    if (tid == T - 1) offs[N] = sums[T - 1];
}

// ---------------- CSR fill (by target node) ----------------
__global__ void fill_kernel(const int* __restrict__ erow, const int* __restrict__ ecol,
                            const int* __restrict__ offs, int* __restrict__ cursor,
                            const float* __restrict__ dinv,
                            int* __restrict__ csr_src, float* __restrict__ csr_norm, int E) {
    int e = blockIdx.x * blockDim.x + threadIdx.x;
    if (e >= E) return;
    int r = erow[e], c = ecol[e];
    int p = atomicAdd(&cursor[c], 1);
    int idx = offs[c] + p;
    csr_src[idx] = r;
    csr_norm[idx] = dinv[r] * dinv[c];
}

// ---------------- weight pack: W[g][k][n] fp32 -> Wt[g][n][k] bf16 hi/lo ----------------
// Wc: [4][256][256] -> WcT. Wml: [Wm|Wl] fused: n<128 from Wm[g][k][n], n>=128 from Wl[g][k][n-128].
__global__ __launch_bounds__(256) void pack_w_kernel(const float* __restrict__ Wc,
                                                     const float* __restrict__ Wm,
                                                     const float* __restrict__ Wl,
                                                     short* __restrict__ WcT_hi,
                                                     short* __restrict__ WcT_lo,
                                                     short* __restrict__ WmlT_hi,
                                                     short* __restrict__ WmlT_lo) {
    int idx = blockIdx.x * 256 + threadIdx.x;  // over 4*256*256
    int g = idx >> 16;
    int n = (idx >> 8) & 255;
    int k = idx & 255;
    float wc = Wc[((size_t)(g * 256 + k) * 256) + n];
    WcT_hi[idx] = (short)bf16_hi_trunc(wc);
    WcT_lo[idx] = (short)bf16_lo_rne(wc);
    float wml = (n < 128) ? Wm[((size_t)(g * 256 + k) * 128) + n]
                          : Wl[((size_t)(g * 256 + k) * 128) + (n - 128)];
    WmlT_hi[idx] = (short)bf16_hi_trunc(wml);
    WmlT_lo[idx] = (short)bf16_lo_rne(wml);
}

// ---------------- split-bf16 MFMA GEMM: C[M,Nc] = A[M,256] @ B[256,Nc] ----------------
// Block tile 128x128, 4 waves, each wave 64x64 via 16x16x32 bf16 MFMA.
// A staged in LDS as hi/lo bf16 (in-kernel split). B read directly from
// pre-packed global Wt_hi/Wt_lo [Nc][256] bf16 (L2-resident, 16B frags).
__global__ __launch_bounds__(256) void gemm_mfma_kernel(const float* __restrict__ A,
                                                        const short* __restrict__ Bt_hi,
                                                        const short* __restrict__ Bt_lo,
                                                        float* __restrict__ C, int M, int Nc) {
    __shared__ __align__(16) short As_hi[128][40];  // [m][k] k-chunk=32, pad->40
    __shared__ __align__(16) short As_lo[128][40];

    int t = threadIdx.x;
    int lane = t & 63;
    int wave = t >> 6;
    int wm = (wave & 1) * 64;
    int wn = (wave >> 1) * 64;
    int row_blk = blockIdx.y * 128;
    int col_blk = blockIdx.x * 128;

    // staging map: thread t -> row rb + 32p, k-quad kq
    int kq = (t & 7) * 4;
    int rb = t >> 3;  // 0..31

    // frag map
    int al = lane & 15;
    int ak = (lane >> 4) * 8;

    floatx4 acc[4][4] = {};

    for (int k0 = 0; k0 < 256; k0 += 32) {
        __syncthreads();  // protect LDS from readers of previous chunk
#pragma unroll
        for (int p = 0; p < 4; ++p) {
            int r = rb + p * 32;
            int gr = row_blk + r;
            float4 v = make_float4(0.f, 0.f, 0.f, 0.f);
            if (gr < M) v = *(const float4*)(A + (size_t)gr * 256 + k0 + kq);
            short4v h4, l4;
            h4[0] = (short)bf16_hi_trunc(v.x); l4[0] = (short)bf16_lo_rne(v.x);
            h4[1] = (short)bf16_hi_trunc(v.y); l4[1] = (short)bf16_lo_rne(v.y);
            h4[2] = (short)bf16_hi_trunc(v.z); l4[2] = (short)bf16_lo_rne(v.z);
            h4[3] = (short)bf16_hi_trunc(v.w); l4[3] = (short)bf16_lo_rne(v.w);
            *(short4v*)&As_hi[r][kq] = h4;
            *(short4v*)&As_lo[r][kq] = l4;
        }
        __syncthreads();

        // B frags from global (weights; L2-resident)
        short8 bh[4], bl[4];
#pragma unroll
        for (int nt = 0; nt < 4; ++nt) {
            const short* ph = Bt_hi + (size_t)(col_blk + wn + nt * 16 + al) * 256 + k0 + ak;
            const short* pl = Bt_lo + (size_t)(col_blk + wn + nt * 16 + al) * 256 + k0 + ak;
            bh[nt] = *(const short8*)ph;
            bl[nt] = *(const short8*)pl;
        }

#pragma unroll
        for (int mt = 0; mt < 4; ++mt) {
            short8 ah = *(const short8*)&As_hi[wm + mt * 16 + al][ak];
            short8 alo = *(const short8*)&As_lo[wm + mt * 16 + al][ak];
#pragma unroll
            for (int nt = 0; nt < 4; ++nt) {
                acc[mt][nt] = __builtin_amdgcn_mfma_f32_16x16x32_bf16(ah, bh[nt], acc[mt][nt], 0, 0, 0);
                acc[mt][nt] = __builtin_amdgcn_mfma_f32_16x16x32_bf16(ah, bl[nt], acc[mt][nt], 0, 0, 0);
                acc[mt][nt] = __builtin_amdgcn_mfma_f32_16x16x32_bf16(alo, bh[nt], acc[mt][nt], 0, 0, 0);
            }
        }
    }

    // epilogue: C/D layout col=lane&15, row=(lane>>4)*4+reg
    int rq = lane >> 4;
#pragma unroll
    for (int mt = 0; mt < 4; ++mt) {
        int rbase = row_blk + wm + mt * 16 + rq * 4;
#pragma unroll
        for (int reg = 0; reg < 4; ++reg) {
            int r = rbase + reg;
            if (r < M) {
#pragma unroll
                for (int nt = 0; nt < 4; ++nt) {
                    C[(size_t)r * Nc + col_blk + wn + nt * 16 + al] = acc[mt][nt][reg];
                }
            }
        }
    }
}

// ---------------- aggregation: 256 channels, one node per block ----------------
__global__ __launch_bounds__(256) void agg_kernel(const float* __restrict__ Hlin,
                                                  const float* __restrict__ dinv,
                                                  const int* __restrict__ offs,
                                                  const int* __restrict__ csr_src,
                                                  const float* __restrict__ csr_norm,
                                                  const float* __restrict__ bias,
                                                  float* __restrict__ Hout) {
    int node = blockIdx.x;
    int c = threadIdx.x;
    float di = dinv[node];
    float acc = bias[c] + di * di * Hlin[(size_t)node * 256 + c];
    int s = offs[node], e = offs[node + 1];
    for (int j = s; j < e; ++j) {
        acc += csr_norm[j] * Hlin[(size_t)csr_src[j] * 256 + c];
    }
    Hout[(size_t)node * 256 + c] = acc;
}

// ---------------- dual aggregation on fused [mu|ls] layout [N,256] ----------------
__global__ __launch_bounds__(256) void agg_dual_kernel(const float* __restrict__ Lin,
                                                       const float* __restrict__ dinv,
                                                       const int* __restrict__ offs,
                                                       const int* __restrict__ csr_src,
                                                       const float* __restrict__ csr_norm,
                                                       const float* __restrict__ bm,
                                                       const float* __restrict__ bl,
                                                       float* __restrict__ out_mu,
                                                       float* __restrict__ out_ls) {
    int node = blockIdx.x;
    int t = threadIdx.x;
    float di = dinv[node];
    float bias = (t < 128) ? bm[t] : bl[t - 128];
    float acc = bias + di * di * Lin[(size_t)node * 256 + t];
    int s = offs[node], e = offs[node + 1];
    for (int j = s; j < e; ++j) {
        acc += csr_norm[j] * Lin[(size_t)csr_src[j] * 256 + t];
    }
    if (t < 128) out_mu[(size_t)node * 128 + t] = acc;
    else         out_ls[(size_t)node * 128 + (t - 128)] = acc;
}

extern "C" void kernel_launch(void* const* d_in, const int* in_sizes, int n_in,
                              void* d_out, int out_size, void* d_ws, size_t ws_size,
                              hipStream_t stream) {
    const int N = NN, E = NE;
    const float* Wc = (const float*)d_in[8];
    const float* bc = (const float*)d_in[9];
    const float* Wm = (const float*)d_in[10];
    const float* bm = (const float*)d_in[11];
    const float* Wl = (const float*)d_in[12];
    const float* bl = (const float*)d_in[13];
    float* out = (float*)d_out;

    // workspace layout (~112 MB)
    float* buf_lin  = (float*)d_ws;                     // N*256
    float* buf_h    = buf_lin + (size_t)N * 256;        // N*256
    float* dinv     = buf_h + (size_t)N * 256;          // N
    int*   cnt      = (int*)(dinv + N);                 // N
    int*   offs     = cnt + N;                          // N+1
    int*   cursor   = offs + N + 1;                     // N
    int*   csr_src  = cursor + N;                       // E
    float* csr_norm = (float*)(csr_src + E);            // E
    short* WcT_hi   = (short*)(csr_norm + E);           // 4*256*256
    short* WcT_lo   = WcT_hi + 4 * 65536;
    short* WmlT_hi  = WcT_lo + 4 * 65536;
    short* WmlT_lo  = WmlT_hi + 4 * 65536;

    // pack weights (all 4 graphs) once
    pack_w_kernel<<<1024, 256, 0, stream>>>(Wc, Wm, Wl, WcT_hi, WcT_lo, WmlT_hi, WmlT_lo);

    for (int g = 0; g < 4; ++g) {
        const float* x = (const float*)d_in[2 * g];
        const int* ei = (const int*)d_in[2 * g + 1];
        const int* erow = ei;       // sources
        const int* ecol = ei + E;   // targets

        hipMemsetAsync(cnt, 0, N * sizeof(int), stream);
        hipMemsetAsync(cursor, 0, N * sizeof(int), stream);
        count_kernel<<<(E + 255) / 256, 256, 0, stream>>>(ecol, cnt, E);
        scan_dinv_kernel<<<1, 1024, 0, stream>>>(cnt, offs, dinv, N);
        fill_kernel<<<(E + 255) / 256, 256, 0, stream>>>(erow, ecol, offs, cursor, dinv,
                                                         csr_src, csr_norm, E);
        // conv1 linear: buf_lin = x @ Wc   [N,256]
        gemm_mfma_kernel<<<dim3(2, (N + 127) / 128), 256, 0, stream>>>(
            x, WcT_hi + (size_t)g * 65536, WcT_lo + (size_t)g * 65536, buf_lin, N, 256);
        // conv1 aggregate: buf_h = A_norm @ buf_lin + bc
        agg_kernel<<<N, 256, 0, stream>>>(buf_lin, dinv, offs, csr_src, csr_norm,
                                          bc + (size_t)g * 256, buf_h);
        // conv2+conv3 linear fused: buf_lin = buf_h @ [Wm|Wl]   [N,256]
        gemm_mfma_kernel<<<dim3(2, (N + 127) / 128), 256, 0, stream>>>(
            buf_h, WmlT_hi + (size_t)g * 65536, WmlT_lo + (size_t)g * 65536, buf_lin, N, 256);
        // dual aggregate
        agg_dual_kernel<<<N, 256, 0, stream>>>(buf_lin, dinv, offs, csr_src, csr_norm,
                                               bm + (size_t)g * 128, bl + (size_t)g * 128,
                                               out + (size_t)g * N * 128,
                                               out + (size_t)(4 + g) * N * 128);
    }
}